// Round 6
// baseline (77.523 us; speedup 1.0000x reference)
//
#include <hip/hip_runtime.h>
#include <cfloat>

// Two rows (1024 floats each) per 64-lane wave. Lane i owns j*256+i*4+{0..3}.
//
// kth selection fast path (exact): t0=1.84 constant; compact candidates
// (x>=t0, E[count]~33) into a per-row LDS slot using ballot+mbcnt offsets
// (no serial scan), bitonic-sort 64 across lanes, kth = rank-16-from-top.
// Fallback (C<16 or C>64, ~0.1% of rows): head-sort + exact value ascent.

typedef float f32x4 __attribute__((ext_vector_type(4)));

static __device__ __forceinline__ float wave_min64(float v) {
#pragma unroll
    for (int d = 1; d < 64; d <<= 1) v = fminf(v, __shfl_xor(v, d));
    return v;
}
static __device__ __forceinline__ float wave_sum64(float v) {
#pragma unroll
    for (int d = 1; d < 64; d <<= 1) v += __shfl_xor(v, d);
    return v;
}
static __device__ __forceinline__ int wave_sum64_i(int v) {
#pragma unroll
    for (int d = 1; d < 64; d <<= 1) v += __shfl_xor(v, d);
    return v;
}
static __device__ __forceinline__ unsigned lanes_below(unsigned long long m) {
    return __builtin_amdgcn_mbcnt_hi((unsigned)(m >> 32),
           __builtin_amdgcn_mbcnt_lo((unsigned)m, 0u));
}

struct R16 { float4 a, b, c, d; };

#define APPLY16(OP) \
    OP(r.a.x) OP(r.a.y) OP(r.a.z) OP(r.a.w) \
    OP(r.b.x) OP(r.b.y) OP(r.b.z) OP(r.b.w) \
    OP(r.c.x) OP(r.c.y) OP(r.c.z) OP(r.c.w) \
    OP(r.d.x) OP(r.d.y) OP(r.d.z) OP(r.d.w)

static __device__ __forceinline__ float kth_of_row(const R16& r, int lane, float* sm) {
    const float t0 = 1.84f;   // E[count >= t0] ~= 33 for iid N(0,1) rows

    // ---- ballot+mbcnt compaction (no serial cross-lane scan) ----
    unsigned base = 0;
#define SLOT(X) { \
        const bool p = (X) >= t0; \
        const unsigned long long m = __ballot(p); \
        if (p) sm[base + lanes_below(m)] = (X); \
        base += (unsigned)__popcll(m); }
    APPLY16(SLOT)
#undef SLOT
    const unsigned C = base;   // wave-uniform

    if (C >= 16 && C <= 64) {
        float y = (lane < (int)C) ? sm[lane] : -FLT_MAX;
        // bitonic sort ascending across lanes (lane 63 = max)
#pragma unroll
        for (int k = 2; k <= 64; k <<= 1) {
#pragma unroll
            for (int j = k >> 1; j > 0; j >>= 1) {
                const float p = __shfl_xor(y, j);
                const bool keep_min = (((lane & k) == 0) == ((lane & j) == 0));
                y = keep_min ? fminf(y, p) : fmaxf(y, p);
            }
        }
        return __shfl(y, 48);   // 16th largest
    }

    // ---- fallback (rare, wave-uniform): head-sort + exact value ascent ----
    float h = -FLT_MAX;
#define HMAX(X) h = fmaxf(h, (X));
    APPLY16(HMAX)
#undef HMAX
#pragma unroll
    for (int k = 2; k <= 64; k <<= 1) {
#pragma unroll
        for (int j = k >> 1; j > 0; j >>= 1) {
            const float p = __shfl_xor(h, j);
            const bool keep_min = (((lane & k) == 0) == ((lane & j) == 0));
            h = keep_min ? fminf(h, p) : fmaxf(h, p);
        }
    }
    const float tl = __shfl(h, 48);   // 16th-largest head: lower bound on kth

    float m = FLT_MAX;
#define CANDMIN(X) m = fminf(m, ((X) >= tl) ? (X) : FLT_MAX);
    APPLY16(CANDMIN)
#undef CANDMIN
    float g = wave_min64(m);
    for (;;) {
        int cnt = 0;
        float nm = FLT_MAX;
#define STEP(X) { const bool gt = (X) > g; cnt += gt ? 1 : 0; nm = fminf(nm, gt ? (X) : FLT_MAX); }
        APPLY16(STEP)
#undef STEP
        if (wave_sum64_i(cnt) <= 15) break;
        g = wave_min64(nm);
    }
    return g;
}

static __device__ __forceinline__ void epilogue(const R16& r, float kth, f32x4* op, int lane) {
    const float z0  = (r.a.x >= kth) ? r.a.x : 0.0f;  const float z1  = (r.a.y >= kth) ? r.a.y : 0.0f;
    const float z2  = (r.a.z >= kth) ? r.a.z : 0.0f;  const float z3  = (r.a.w >= kth) ? r.a.w : 0.0f;
    const float z4  = (r.b.x >= kth) ? r.b.x : 0.0f;  const float z5  = (r.b.y >= kth) ? r.b.y : 0.0f;
    const float z6  = (r.b.z >= kth) ? r.b.z : 0.0f;  const float z7  = (r.b.w >= kth) ? r.b.w : 0.0f;
    const float z8  = (r.c.x >= kth) ? r.c.x : 0.0f;  const float z9  = (r.c.y >= kth) ? r.c.y : 0.0f;
    const float z10 = (r.c.z >= kth) ? r.c.z : 0.0f;  const float z11 = (r.c.w >= kth) ? r.c.w : 0.0f;
    const float z12 = (r.d.x >= kth) ? r.d.x : 0.0f;  const float z13 = (r.d.y >= kth) ? r.d.y : 0.0f;
    const float z14 = (r.d.z >= kth) ? r.d.z : 0.0f;  const float z15 = (r.d.w >= kth) ? r.d.w : 0.0f;

    float s = (((z0 + z1) + (z2 + z3)) + ((z4 + z5) + (z6 + z7)))
            + (((z8 + z9) + (z10 + z11)) + ((z12 + z13) + (z14 + z15)));
    s = wave_sum64(s);
    const float inv = 1.0f / s;

    f32x4 o;
    o.x = z0 * inv;  o.y = z1 * inv;  o.z = z2 * inv;  o.w = z3 * inv;
    __builtin_nontemporal_store(o, &op[lane]);
    o.x = z4 * inv;  o.y = z5 * inv;  o.z = z6 * inv;  o.w = z7 * inv;
    __builtin_nontemporal_store(o, &op[64 + lane]);
    o.x = z8 * inv;  o.y = z9 * inv;  o.z = z10 * inv; o.w = z11 * inv;
    __builtin_nontemporal_store(o, &op[128 + lane]);
    o.x = z12 * inv; o.y = z13 * inv; o.z = z14 * inv; o.w = z15 * inv;
    __builtin_nontemporal_store(o, &op[192 + lane]);
}

__global__ __launch_bounds__(256) void kmax_norm_kernel(const float* __restrict__ in,
                                                        float* __restrict__ out,
                                                        int nrows) {
    __shared__ float smbuf[8][64];

    const int lane = threadIdx.x & 63;
    const int wid  = threadIdx.x >> 6;
    const int rowA = (blockIdx.x * 4 + wid) * 2;
    const int rowB = rowA + 1;
    if (rowA >= nrows) return;
    const bool hasB = (rowB < nrows);

    const float4* __restrict__ rpA = reinterpret_cast<const float4*>(in) + (size_t)rowA * 256;
    const float4* __restrict__ rpB = reinterpret_cast<const float4*>(in) + (size_t)rowB * 256;

    // Issue all 8 loads up front (2x memory-level parallelism).
    R16 A, B;
    A.a = rpA[lane];       A.b = rpA[64 + lane];
    A.c = rpA[128 + lane]; A.d = rpA[192 + lane];
    if (hasB) {
        B.a = rpB[lane];       B.b = rpB[64 + lane];
        B.c = rpB[128 + lane]; B.d = rpB[192 + lane];
    }

    const float kthA = kth_of_row(A, lane, smbuf[2 * wid]);
    const float kthB = hasB ? kth_of_row(B, lane, smbuf[2 * wid + 1]) : 0.0f;

    f32x4* __restrict__ opA = reinterpret_cast<f32x4*>(out) + (size_t)rowA * 256;
    epilogue(A, kthA, opA, lane);
    if (hasB) {
        f32x4* __restrict__ opB = reinterpret_cast<f32x4*>(out) + (size_t)rowB * 256;
        epilogue(B, kthB, opB, lane);
    }
}

extern "C" void kernel_launch(void* const* d_in, const int* in_sizes, int n_in,
                              void* d_out, int out_size, void* d_ws, size_t ws_size,
                              hipStream_t stream) {
    (void)n_in; (void)d_ws; (void)ws_size; (void)out_size;
    const float* in = (const float*)d_in[0];
    float* out = (float*)d_out;
    const int nrows = in_sizes[0] / 1024;            // 16*4096 = 65536
    const int blocks = (nrows + 7) / 8;              // 8 rows per 256-thread block
    kmax_norm_kernel<<<blocks, 256, 0, stream>>>(in, out, nrows);
}

// Round 7
// 74.657 us; speedup vs baseline: 1.0384x; 1.0384x over previous
//
#include <hip/hip_runtime.h>
#include <cfloat>

// One 64-lane wave per row of 1024 floats; lane i owns j*256 + i*4 + {0..3}.
//
// kth selection fast path (exact): t0 = 1.84 constant; compact candidates
// (x >= t0, E[count] ~ 33 for iid N(0,1)) into a per-wave LDS slot using
// ballot+mbcnt offsets (no serial cross-lane scan), bitonic-sort 64 across
// lanes, kth = rank-16-from-top (sorted[48]); valid when 16 <= C <= 64 since
// all top-16 values are >= t0. Fallback (rare, wave-uniform): head-sort +
// exact value-ascent.

typedef float f32x4 __attribute__((ext_vector_type(4)));

static __device__ __forceinline__ float wave_min64(float v) {
#pragma unroll
    for (int d = 1; d < 64; d <<= 1) v = fminf(v, __shfl_xor(v, d));
    return v;
}
static __device__ __forceinline__ float wave_sum64(float v) {
#pragma unroll
    for (int d = 1; d < 64; d <<= 1) v += __shfl_xor(v, d);
    return v;
}
static __device__ __forceinline__ int wave_sum64_i(int v) {
#pragma unroll
    for (int d = 1; d < 64; d <<= 1) v += __shfl_xor(v, d);
    return v;
}
static __device__ __forceinline__ unsigned lanes_below(unsigned long long m) {
    return __builtin_amdgcn_mbcnt_hi((unsigned)(m >> 32),
           __builtin_amdgcn_mbcnt_lo((unsigned)m, 0u));
}

__global__ __launch_bounds__(256) void kmax_norm_kernel(const float* __restrict__ in,
                                                        float* __restrict__ out,
                                                        int nrows) {
    __shared__ float smbuf[4][64];

    const int lane = threadIdx.x & 63;
    const int wid  = threadIdx.x >> 6;
    const int row  = blockIdx.x * 4 + wid;
    if (row >= nrows) return;
    float* const sm = smbuf[wid];

    const float4* __restrict__ rp = reinterpret_cast<const float4*>(in) + (size_t)row * 256;
    f32x4* __restrict__ op        = reinterpret_cast<f32x4*>(out) + (size_t)row * 256;

    const float4 v0 = rp[lane];
    const float4 v1 = rp[64 + lane];
    const float4 v2 = rp[128 + lane];
    const float4 v3 = rp[192 + lane];

    const float x0  = v0.x, x1  = v0.y, x2  = v0.z, x3  = v0.w;
    const float x4  = v1.x, x5  = v1.y, x6  = v1.z, x7  = v1.w;
    const float x8  = v2.x, x9  = v2.y, x10 = v2.z, x11 = v2.w;
    const float x12 = v3.x, x13 = v3.y, x14 = v3.z, x15 = v3.w;

#define APPLY16(OP) \
    OP(x0)  OP(x1)  OP(x2)  OP(x3)  OP(x4)  OP(x5)  OP(x6)  OP(x7) \
    OP(x8)  OP(x9)  OP(x10) OP(x11) OP(x12) OP(x13) OP(x14) OP(x15)

    const float t0 = 1.84f;   // E[count >= t0] ~= 33 per row

    // ---- ballot+mbcnt compaction into LDS (no serial scan) ----
    unsigned base = 0;
#define SLOT(X) { \
        const bool p = (X) >= t0; \
        const unsigned long long m = __ballot(p); \
        if (p) sm[base + lanes_below(m)] = (X); \
        base += (unsigned)__popcll(m); }
    APPLY16(SLOT)
#undef SLOT
    const unsigned C = base;   // wave-uniform

    float kth;
    if (C >= 16 && C <= 64) {
        float y = (lane < (int)C) ? sm[lane] : -FLT_MAX;
        // bitonic sort ascending across lanes (lane 63 = max)
#pragma unroll
        for (int k = 2; k <= 64; k <<= 1) {
#pragma unroll
            for (int j = k >> 1; j > 0; j >>= 1) {
                const float p = __shfl_xor(y, j);
                const bool keep_min = (((lane & k) == 0) == ((lane & j) == 0));
                y = keep_min ? fminf(y, p) : fmaxf(y, p);
            }
        }
        kth = __shfl(y, 48);   // 16th largest
    } else {
        // ---- fallback (rare, wave-uniform): head-sort + exact value ascent ----
        float h = -FLT_MAX;
#define HMAX(X) h = fmaxf(h, (X));
        APPLY16(HMAX)
#undef HMAX
#pragma unroll
        for (int k = 2; k <= 64; k <<= 1) {
#pragma unroll
            for (int j = k >> 1; j > 0; j >>= 1) {
                const float p = __shfl_xor(h, j);
                const bool keep_min = (((lane & k) == 0) == ((lane & j) == 0));
                h = keep_min ? fminf(h, p) : fmaxf(h, p);
            }
        }
        const float tl = __shfl(h, 48);   // 16th-largest head: lower bound on kth

        float m = FLT_MAX;
#define CANDMIN(X) m = fminf(m, ((X) >= tl) ? (X) : FLT_MAX);
        APPLY16(CANDMIN)
#undef CANDMIN
        float g = wave_min64(m);
        for (;;) {
            int cnt = 0;
            float nm = FLT_MAX;
#define STEP(X) { const bool gt = (X) > g; cnt += gt ? 1 : 0; nm = fminf(nm, gt ? (X) : FLT_MAX); }
            APPLY16(STEP)
#undef STEP
            if (wave_sum64_i(cnt) <= 15) break;
            g = wave_min64(nm);
        }
        kth = g;
    }
#undef APPLY16

    // ---- fused mask + sum + normalize + store ----
    const float z0  = (x0  >= kth) ? x0  : 0.0f;  const float z1  = (x1  >= kth) ? x1  : 0.0f;
    const float z2  = (x2  >= kth) ? x2  : 0.0f;  const float z3  = (x3  >= kth) ? x3  : 0.0f;
    const float z4  = (x4  >= kth) ? x4  : 0.0f;  const float z5  = (x5  >= kth) ? x5  : 0.0f;
    const float z6  = (x6  >= kth) ? x6  : 0.0f;  const float z7  = (x7  >= kth) ? x7  : 0.0f;
    const float z8  = (x8  >= kth) ? x8  : 0.0f;  const float z9  = (x9  >= kth) ? x9  : 0.0f;
    const float z10 = (x10 >= kth) ? x10 : 0.0f;  const float z11 = (x11 >= kth) ? x11 : 0.0f;
    const float z12 = (x12 >= kth) ? x12 : 0.0f;  const float z13 = (x13 >= kth) ? x13 : 0.0f;
    const float z14 = (x14 >= kth) ? x14 : 0.0f;  const float z15 = (x15 >= kth) ? x15 : 0.0f;

    float s = (((z0 + z1) + (z2 + z3)) + ((z4 + z5) + (z6 + z7)))
            + (((z8 + z9) + (z10 + z11)) + ((z12 + z13) + (z14 + z15)));
    s = wave_sum64(s);
    const float inv = 1.0f / s;

    f32x4 o;
    o.x = z0 * inv;  o.y = z1 * inv;  o.z = z2 * inv;  o.w = z3 * inv;
    __builtin_nontemporal_store(o, &op[lane]);
    o.x = z4 * inv;  o.y = z5 * inv;  o.z = z6 * inv;  o.w = z7 * inv;
    __builtin_nontemporal_store(o, &op[64 + lane]);
    o.x = z8 * inv;  o.y = z9 * inv;  o.z = z10 * inv; o.w = z11 * inv;
    __builtin_nontemporal_store(o, &op[128 + lane]);
    o.x = z12 * inv; o.y = z13 * inv; o.z = z14 * inv; o.w = z15 * inv;
    __builtin_nontemporal_store(o, &op[192 + lane]);
}

extern "C" void kernel_launch(void* const* d_in, const int* in_sizes, int n_in,
                              void* d_out, int out_size, void* d_ws, size_t ws_size,
                              hipStream_t stream) {
    (void)n_in; (void)d_ws; (void)ws_size; (void)out_size;
    const float* in = (const float*)d_in[0];
    float* out = (float*)d_out;
    const int nrows = in_sizes[0] / 1024;           // 16*4096 = 65536
    const int blocks = (nrows + 3) / 4;             // 4 waves (rows) per 256-thread block
    kmax_norm_kernel<<<blocks, 256, 0, stream>>>(in, out, nrows);
}